// Round 22
// baseline (136.626 us; speedup 1.0000x reference)
//
#include <hip/hip_runtime.h>

// Wav2Vec2 Gumbel VQ — round 22: r21 + 2-buffer K-loop (ISSUE after barrier)
// -> 52KB LDS -> 3 blocks/CU. This variable was confounded in r18 by the
// __threadfence regression (r19 proved fence alone = 630us); now isolated.
// Race-safe: ISSUE(c+1) targets buf (c-1)&1 whose reads completed before the
// barrier (lgkm waits precede each wave's MFMAs). All else identical to r21.

#define GG   2
#define KK   320
#define NN   65536
#define DD   512
#define DPG  128
#define EPSL 1e-7f
#define NCPY 8
#define BUFB 24576   // bytes per LDS chunk buffer: 4 A frags + 20 B frags

typedef __attribute__((ext_vector_type(8))) short bf16x8;   // 8 x bf16
typedef __attribute__((ext_vector_type(4))) float f32x4;
typedef __attribute__((address_space(1))) void glb_void;
typedef __attribute__((address_space(3))) void lds_void;

static __device__ __forceinline__ unsigned short f2bf_rne(float f) {
    unsigned u = __float_as_uint(f);
    u += 0x7FFFu + ((u >> 16) & 1u);
    return (unsigned short)(u >> 16);
}

static __device__ __forceinline__ bf16x8 pack8_rne(float4 v0, float4 v1) {
    union { unsigned short s[8]; bf16x8 b; } u;
    u.s[0] = f2bf_rne(v0.x); u.s[1] = f2bf_rne(v0.y);
    u.s[2] = f2bf_rne(v0.z); u.s[3] = f2bf_rne(v0.w);
    u.s[4] = f2bf_rne(v1.x); u.s[5] = f2bf_rne(v1.y);
    u.s[6] = f2bf_rne(v1.z); u.s[7] = f2bf_rne(v1.w);
    return u.b;
}

// monotone uint map: f1 < f2  <=>  ordf(f1) < ordf(f2)
static __device__ __forceinline__ unsigned ordf(float f) {
    unsigned u = __float_as_uint(f);
    return (u & 0x80000000u) ? ~u : (u | 0x80000000u);
}

// ---------- fused prep: H->bf16 row-major (sequential), W->Wf frags, misc ----------
__global__ __launch_bounds__(256) void prep_all(
    const float* __restrict__ H, short* __restrict__ Hbf,
    const float* __restrict__ W, short* __restrict__ Wf,
    float* __restrict__ marg, const int* __restrict__ mask,
    float* __restrict__ cnt_out, int* __restrict__ done)
{
    const int b = blockIdx.x, tid = threadIdx.x;
    if (b < 16384) {
        const size_t base = ((size_t)b * 256 + tid) * 8;
        float4 v0 = *(const float4*)(H + base);
        float4 v1 = *(const float4*)(H + base + 4);
        *(bf16x8*)(Hbf + base) = pack8_rne(v0, v1);
    } else if (b < 16544) {
        int gt = (b - 16384) * 256 + tid;
        int w  = gt >> 6, l = gt & 63;
        int col = 16 * (w >> 4) + (l & 15);
        int k0  = 32 * (w & 15) + 8 * (l >> 4);
        const float* src = W + (size_t)col * DD + k0;
        float4 v0 = *(const float4*)(src);
        float4 v1 = *(const float4*)(src + 4);
        *(bf16x8*)(Wf + (size_t)w * 512 + (size_t)l * 8) = pack8_rne(v0, v1);
    } else {
        __shared__ float red[256];
        for (int i = tid; i < NCPY * GG * KK; i += 256) marg[i] = 0.f;
        if (tid == 0) *done = 0;
        const int4* m4 = (const int4*)mask;
        int c = 0;
#pragma unroll 4
        for (int i = tid; i < NN / 4; i += 256) {
            int4 v = m4[i];
            c += (v.x != 0) + (v.y != 0) + (v.z != 0) + (v.w != 0);
        }
        red[tid] = (float)c;
        __syncthreads();
        for (int s = 128; s > 0; s >>= 1) {
            if (tid < s) red[tid] += red[tid + s];
            __syncthreads();
        }
        if (tid == 0) *cnt_out = red[0];
    }
}

// ---------- main: GEMM + softmax/argmax/marginal + gather + last-block finalize ----------
// grid 2048 = 1024 row-tiles (64 rows) x 2 groups; 512 thr = 8 waves.
// 2-buffer K-loop: vmcnt(0) [chunk c landed] -> s_barrier -> ISSUE(c+1) -> COMPUTE(c).
__global__ __launch_bounds__(512, 4) void vq_main(
    const short* Hbf, const int* __restrict__ mask,
    const float* __restrict__ gumbel, const short* __restrict__ Wf,
    const float* __restrict__ bias, const float* __restrict__ cv,
    int* __restrict__ idxW, float* marg,
    int fused, float* __restrict__ out,
    const float* __restrict__ cnt_in, int* done, float* __restrict__ perp_out)
{
    __shared__ __align__(16) char smem[2 * BUFB];     // 48 KB: 2 chunk buffers
    __shared__ float    red_s[256];
    __shared__ unsigned red_k[256];
    __shared__ float    wrowS[64];
    __shared__ int      idxf[64];
    __shared__ int      lastflag;

    const int tid = threadIdx.x;
    const int l   = tid & 63, wid = tid >> 6;
    const int rh  = wid >> 2, hc = wid & 3;
    const int g   = blockIdx.x & 1;
    const int T   = blockIdx.x >> 1;
    const int n0  = T * 64;
    const int q   = l >> 4,  ln = l & 15;

    // hoisted per-lane DMA source bases (t=0) + per-chunk byte strides.
    // k<4: A frag from row-major Hbf (lane l -> row n0+16k+(l&15), col 8*(l>>4)); step 64B.
    // k>=4: B frag from fragment-ordered Wf; step 1024B.
    const short* gsrc0[3];
    int stepB[3];
#pragma unroll
    for (int j = 0; j < 3; ++j) {
        const int k = wid * 3 + j;
        if (k < 4) {
            gsrc0[j] = Hbf + (size_t)(n0 + 16 * k + (l & 15)) * 512 + 8 * (l >> 4);
            stepB[j] = 64;
        } else {
            gsrc0[j] = Wf + (size_t)((g * 20 + (k - 4)) * 16) * 512 + (size_t)l * 8;
            stepB[j] = 1024;
        }
    }

#define ISSUE(t_, b_)                                                          \
    { _Pragma("unroll")                                                        \
      for (int j = 0; j < 3; ++j) {                                            \
          const int k = wid * 3 + j;                                           \
          const short* gsrc = (const short*)((const char*)gsrc0[j] + (t_) * stepB[j]); \
          char* ldst = smem + (b_)*BUFB + k * 1024;                            \
          __builtin_amdgcn_global_load_lds((const glb_void*)gsrc, (lds_void*)ldst, 16, 0, 0); \
      } }

    f32x4 acc[2][5];
    const f32x4 vzero = {0.f, 0.f, 0.f, 0.f};
#pragma unroll
    for (int a = 0; a < 2; ++a)
#pragma unroll
        for (int b = 0; b < 5; ++b) acc[a][b] = vzero;

#define COMPUTE(b_)                                                            \
    { const char* bb_ = smem + (b_)*BUFB;                                      \
      bf16x8 Ar[2], Br[5];                                                     \
      _Pragma("unroll")                                                        \
      for (int rf = 0; rf < 2; ++rf)                                           \
          Ar[rf] = *(const bf16x8*)(bb_ + (rh * 2 + rf) * 1024 + l * 16);      \
      _Pragma("unroll")                                                        \
      for (int cf = 0; cf < 5; ++cf)                                           \
          Br[cf] = *(const bf16x8*)(bb_ + 4096 + (hc * 5 + cf) * 1024 + l * 16); \
      __builtin_amdgcn_s_setprio(1);                                           \
      _Pragma("unroll")                                                        \
      for (int cf = 0; cf < 5; ++cf) {                                         \
          acc[0][cf] = __builtin_amdgcn_mfma_f32_16x16x32_bf16(Ar[0], Br[cf], acc[0][cf], 0, 0, 0); \
          acc[1][cf] = __builtin_amdgcn_mfma_f32_16x16x32_bf16(Ar[1], Br[cf], acc[1][cf], 0, 0, 0); } \
      __builtin_amdgcn_s_setprio(0); }

    ISSUE(0, 0)
#pragma unroll 1
    for (int c = 0; c < 16; ++c) {
        asm volatile("s_waitcnt vmcnt(0)" ::: "memory");   // chunk c landed (only it outstanding)
        __builtin_amdgcn_sched_barrier(0);
        __builtin_amdgcn_s_barrier();     // all waves' reads of buf (c+1)&1 (chunk c-1) done
        if (c + 1 < 16) ISSUE(c + 1, (c + 1) & 1)
        __builtin_amdgcn_sched_barrier(0);
        COMPUTE(c & 1)
    }

    // ---- epilogue: bias + gumbel, no-max softmax (exp into acc), packed-key argmax ----
    float bb[5];
#pragma unroll
    for (int cf = 0; cf < 5; ++cf) bb[cf] = bias[g * KK + hc * 80 + 16 * cf + ln];

    float gum[8][5];
#pragma unroll
    for (int rf = 0; rf < 2; ++rf)
#pragma unroll
        for (int reg = 0; reg < 4; ++reg) {
            const int row = 32 * rh + 16 * rf + 4 * q + reg;
            const float* gp = gumbel + ((size_t)(n0 + row) * GG + g) * KK + hc * 80 + ln;
#pragma unroll
            for (int cf = 0; cf < 5; ++cf) gum[rf * 4 + reg][cf] = gp[16 * cf];
        }
    __builtin_amdgcn_sched_barrier(0);

#pragma unroll
    for (int cf = 0; cf < 5; ++cf)
#pragma unroll
        for (int rf = 0; rf < 2; ++rf) {
            acc[rf][cf][0] += bb[cf]; acc[rf][cf][1] += bb[cf];
            acc[rf][cf][2] += bb[cf]; acc[rf][cf][3] += bb[cf];
        }

#pragma unroll
    for (int rf = 0; rf < 2; ++rf) {
#pragma unroll
        for (int reg = 0; reg < 4; ++reg) {
            const int row = 32 * rh + 16 * rf + 4 * q + reg;
            float s = 0.f, zm = -3.0e38f;
            int zi = 0;
#pragma unroll
            for (int cf = 0; cf < 5; ++cf) {
                float v = acc[rf][cf][reg];
                float z = v + gum[rf * 4 + reg][cf];
                if (z > zm) { zm = z; zi = hc * 80 + 16 * cf + ln; }  // in-lane: exact, first-index
                float e = __expf(v);
                s += e;
                acc[rf][cf][reg] = e;              // reuse in marginal
            }
            unsigned key = (ordf(zm) & 0xFFFFFE00u) | (unsigned)(511 - zi);
#pragma unroll
            for (int d = 1; d <= 8; d <<= 1) {
                s += __shfl_xor(s, d);
                unsigned ko = (unsigned)__shfl_xor((int)key, d);
                key = key > ko ? key : ko;
            }
            if (ln == 0) {
                const int base = row * 4 + hc;
                red_s[base] = s;
                red_k[base] = key;
            }
        }
    }
    __syncthreads();

    if (tid < 64) {
        const int b0 = tid * 4;
        float Z = red_s[b0] + red_s[b0 + 1] + red_s[b0 + 2] + red_s[b0 + 3];
        unsigned km = red_k[b0];
        km = km > red_k[b0 + 1] ? km : red_k[b0 + 1];
        km = km > red_k[b0 + 2] ? km : red_k[b0 + 2];
        km = km > red_k[b0 + 3] ? km : red_k[b0 + 3];
        const int ib = 511 - (int)(km & 511u);
        idxf[tid]  = ib;
        if (!fused) idxW[(size_t)(n0 + tid) * GG + g] = ib;
        wrowS[tid] = ((mask[n0 + tid] != 0) ? 1.0f : 0.0f) / Z;
    }
    __syncthreads();

    // ---- marginal (acc holds exp) ----
    float cs[5] = {0.f, 0.f, 0.f, 0.f, 0.f};
#pragma unroll
    for (int rf = 0; rf < 2; ++rf) {
#pragma unroll
        for (int reg = 0; reg < 4; ++reg) {
            const int row = 32 * rh + 16 * rf + 4 * q + reg;
            const float wv = wrowS[row];
#pragma unroll
            for (int cf = 0; cf < 5; ++cf)
                cs[cf] += acc[rf][cf][reg] * wv;
        }
    }
    {
        float* mc = marg + (size_t)(blockIdx.x & (NCPY - 1)) * (GG * KK);
#pragma unroll
        for (int cf = 0; cf < 5; ++cf) {
            float v = cs[cf];
            v += __shfl_xor(v, 16);
            v += __shfl_xor(v, 32);
            if (l < 16) atomicAdd(&mc[g * KK + hc * 80 + 16 * cf + l], v);
        }
    }

    // ---- fused codevector gather (Path A: out does NOT alias Hbf) ----
    if (fused) {
#pragma unroll
        for (int i = 0; i < 4; ++i) {
            const int e = tid + 512 * i;           // 2048 float4: 64 rows x 32
            const int row = e >> 5, d4 = e & 31;
            const float4 v = ((const float4*)cv)[((size_t)g * KK + idxf[row]) * 32 + d4];
            ((float4*)(out + (size_t)(n0 + row) * 256 + g * DPG))[d4] = v;
        }
    }

    // ---- last-block perplexity finalize (no __threadfence — r19 lesson) ----
    asm volatile("s_waitcnt vmcnt(0)" ::: "memory");   // marg atomics performed
    __syncthreads();
    if (tid == 0) {
        int old = atomicAdd(done, 1);
        lastflag = (old == 2047) ? 1 : 0;
    }
    __syncthreads();
    if (lastflag) {
        const float invc = 1.0f / cnt_in[0];
        float hg[GG];
#pragma unroll
        for (int gg = 0; gg < GG; ++gg) {
            float h = 0.f;
            for (int c = tid; c < KK; c += 512) {
                float m = 0.f;
#pragma unroll
                for (int x = 0; x < NCPY; ++x)
                    m += atomicAdd(&marg[x * (GG * KK) + gg * KK + c], 0.0f);
                m *= invc;
                h += m * logf(m + EPSL);
            }
#pragma unroll
            for (int d = 1; d < 64; d <<= 1) h += __shfl_xor(h, d);
            if (l == 0) red_s[wid] = h;
            __syncthreads();
            if (tid == 0) {
                float t = 0.f;
                for (int wv = 0; wv < 8; ++wv) t += red_s[wv];
                red_s[64 + gg] = t;
            }
            __syncthreads();
            hg[gg] = red_s[64 + gg];
        }
        if (tid == 0) perp_out[0] = expf(-hg[0]) + expf(-hg[1]);   // base-e
    }
}

// ---------- Path B gather (pure) ----------
__global__ __launch_bounds__(256) void gather_kernel(
    const int* __restrict__ idxW, const float* __restrict__ cv,
    float* __restrict__ out)
{
    const int e = blockIdx.x * 256 + threadIdx.x;     // 4,194,304 float4 slots
    const int n = e >> 6, s4 = e & 63, g = s4 >> 5, d4 = s4 & 31;
    const int idx = idxW[(size_t)n * GG + g];
    const float4 v = ((const float4*)cv)[((size_t)g * KK + idx) * 32 + d4];
    ((float4*)out)[e] = v;
}

extern "C" void kernel_launch(void* const* d_in, const int* in_sizes, int n_in,
                              void* d_out, int out_size, void* d_ws, size_t ws_size,
                              hipStream_t stream)
{
    const float* H      = (const float*)d_in[0];   // (32,2048,512) f32
    const int*   mask   = (const int*)d_in[1];     // (32,2048) bool->int32
    const float* gumbel = (const float*)d_in[2];   // (131072,320) f32
    const float* W      = (const float*)d_in[3];   // (640,512) f32
    const float* bias   = (const float*)d_in[4];   // (640,) f32
    const float* cv     = (const float*)d_in[5];   // (1,640,128) f32

    float*  out  = (float*)d_out;                  // 16,777,216 + 1 floats
    float*  marg = (float*)d_ws;                   // 8 copies x 640 f32 (20.5 KB)
    float*  cnt  = (float*)((char*)d_ws + 24576);  // mask count
    int*    done = (int*)((char*)d_ws + 24580);    // completion counter
    short*  Wf   = (short*)((char*)d_ws + 32768);  // 0.655 MB bf16 frags
    int*    idxW = (int*)((char*)d_ws + 32768 + 655360);  // 131072 ints

    const size_t hbf_off  = 2 * 1024 * 1024;
    const size_t hbf_need = hbf_off + (size_t)64 * 1024 * 1024;
    const int fused = (ws_size >= hbf_need) ? 1 : 0;
    short* Hbf = fused ? (short*)((char*)d_ws + hbf_off) : (short*)d_out;

    prep_all<<<16545, 256, 0, stream>>>(H, Hbf, W, Wf, marg, mask, cnt, done);
    vq_main<<<2048, 512, 0, stream>>>(Hbf, mask, gumbel, Wf, bias, cv, idxW, marg,
                                      fused, out, cnt, done,
                                      out + (size_t)NN * GG * DPG);
    if (!fused)
        gather_kernel<<<16384, 256, 0, stream>>>(idxW, cv, out);
}

// Round 23
// 135.638 us; speedup vs baseline: 1.0073x; 1.0073x over previous
//
#include <hip/hip_runtime.h>

// Wav2Vec2 Gumbel VQ — round 23: r21 (best, 132.3us) + bijective XCD swizzle:
// work id s = (b%8)*256 + b/8 puts both group-blocks of tile T (s=2T,2T+1) on
// the SAME XCD -> shared L2 for the 64KB Hbf tile (default round-robin split
// them across XCDs, double-fetching Hbf). Pure permutation; order-free sinks.

#define GG   2
#define KK   320
#define NN   65536
#define DD   512
#define DPG  128
#define EPSL 1e-7f
#define NCPY 8
#define BUFB 24576   // bytes per LDS chunk buffer: 4 A frags + 20 B frags

typedef __attribute__((ext_vector_type(8))) short bf16x8;   // 8 x bf16
typedef __attribute__((ext_vector_type(4))) float f32x4;
typedef __attribute__((address_space(1))) void glb_void;
typedef __attribute__((address_space(3))) void lds_void;

static __device__ __forceinline__ unsigned short f2bf_rne(float f) {
    unsigned u = __float_as_uint(f);
    u += 0x7FFFu + ((u >> 16) & 1u);
    return (unsigned short)(u >> 16);
}

static __device__ __forceinline__ bf16x8 pack8_rne(float4 v0, float4 v1) {
    union { unsigned short s[8]; bf16x8 b; } u;
    u.s[0] = f2bf_rne(v0.x); u.s[1] = f2bf_rne(v0.y);
    u.s[2] = f2bf_rne(v0.z); u.s[3] = f2bf_rne(v0.w);
    u.s[4] = f2bf_rne(v1.x); u.s[5] = f2bf_rne(v1.y);
    u.s[6] = f2bf_rne(v1.z); u.s[7] = f2bf_rne(v1.w);
    return u.b;
}

// monotone uint map: f1 < f2  <=>  ordf(f1) < ordf(f2)
static __device__ __forceinline__ unsigned ordf(float f) {
    unsigned u = __float_as_uint(f);
    return (u & 0x80000000u) ? ~u : (u | 0x80000000u);
}

// ---------- fused prep: H->bf16 row-major (sequential), W->Wf frags, misc ----------
__global__ __launch_bounds__(256) void prep_all(
    const float* __restrict__ H, short* __restrict__ Hbf,
    const float* __restrict__ W, short* __restrict__ Wf,
    float* __restrict__ marg, const int* __restrict__ mask,
    float* __restrict__ cnt_out, int* __restrict__ done)
{
    const int b = blockIdx.x, tid = threadIdx.x;
    if (b < 16384) {
        const size_t base = ((size_t)b * 256 + tid) * 8;
        float4 v0 = *(const float4*)(H + base);
        float4 v1 = *(const float4*)(H + base + 4);
        *(bf16x8*)(Hbf + base) = pack8_rne(v0, v1);
    } else if (b < 16544) {
        int gt = (b - 16384) * 256 + tid;
        int w  = gt >> 6, l = gt & 63;
        int col = 16 * (w >> 4) + (l & 15);
        int k0  = 32 * (w & 15) + 8 * (l >> 4);
        const float* src = W + (size_t)col * DD + k0;
        float4 v0 = *(const float4*)(src);
        float4 v1 = *(const float4*)(src + 4);
        *(bf16x8*)(Wf + (size_t)w * 512 + (size_t)l * 8) = pack8_rne(v0, v1);
    } else {
        __shared__ float red[256];
        for (int i = tid; i < NCPY * GG * KK; i += 256) marg[i] = 0.f;
        if (tid == 0) *done = 0;
        const int4* m4 = (const int4*)mask;
        int c = 0;
#pragma unroll 4
        for (int i = tid; i < NN / 4; i += 256) {
            int4 v = m4[i];
            c += (v.x != 0) + (v.y != 0) + (v.z != 0) + (v.w != 0);
        }
        red[tid] = (float)c;
        __syncthreads();
        for (int s = 128; s > 0; s >>= 1) {
            if (tid < s) red[tid] += red[tid + s];
            __syncthreads();
        }
        if (tid == 0) *cnt_out = red[0];
    }
}

// ---------- main: GEMM + softmax/argmax/marginal + gather + last-block finalize ----------
// grid 2048 = 1024 row-tiles (64 rows) x 2 groups; 512 thr = 8 waves.
// K-loop (r16/r21 proven): ISSUE(c+1) -> vmcnt(3) -> raw s_barrier -> COMPUTE(c).
// Work id XCD-swizzled so tile pairs share an XCD L2.
__global__ __launch_bounds__(512, 4) void vq_main(
    const short* Hbf, const int* __restrict__ mask,
    const float* __restrict__ gumbel, const short* __restrict__ Wf,
    const float* __restrict__ bias, const float* __restrict__ cv,
    int* __restrict__ idxW, float* marg,
    int fused, float* __restrict__ out,
    const float* __restrict__ cnt_in, int* done, float* __restrict__ perp_out)
{
    __shared__ __align__(16) char smem[3 * BUFB];     // 72 KB: 3 chunk buffers
    __shared__ float    red_s[256];
    __shared__ unsigned red_k[256];
    __shared__ float    wrowS[64];
    __shared__ int      idxf[64];
    __shared__ int      lastflag;

    const int tid = threadIdx.x;
    const int l   = tid & 63, wid = tid >> 6;
    const int rh  = wid >> 2, hc = wid & 3;
    // bijective XCD swizzle: HW round-robins blockIdx%8 across XCDs; remap so
    // each XCD gets 256 CONSECUTIVE work ids -> tile pairs (2T,2T+1) co-located.
    const int s_id = (blockIdx.x & 7) * 256 + (blockIdx.x >> 3);
    const int g   = s_id & 1;
    const int T   = s_id >> 1;
    const int n0  = T * 64;
    const int q   = l >> 4,  ln = l & 15;

    // hoisted per-lane DMA source bases (t=0) + per-chunk byte strides.
    // k<4: A frag from row-major Hbf (lane l -> row n0+16k+(l&15), col 8*(l>>4)); step 64B.
    // k>=4: B frag from fragment-ordered Wf; step 1024B.
    const short* gsrc0[3];
    int stepB[3];
#pragma unroll
    for (int j = 0; j < 3; ++j) {
        const int k = wid * 3 + j;
        if (k < 4) {
            gsrc0[j] = Hbf + (size_t)(n0 + 16 * k + (l & 15)) * 512 + 8 * (l >> 4);
            stepB[j] = 64;
        } else {
            gsrc0[j] = Wf + (size_t)((g * 20 + (k - 4)) * 16) * 512 + (size_t)l * 8;
            stepB[j] = 1024;
        }
    }

#define ISSUE(t_, b_)                                                          \
    { _Pragma("unroll")                                                        \
      for (int j = 0; j < 3; ++j) {                                            \
          const int k = wid * 3 + j;                                           \
          const short* gsrc = (const short*)((const char*)gsrc0[j] + (t_) * stepB[j]); \
          char* ldst = smem + (b_)*BUFB + k * 1024;                            \
          __builtin_amdgcn_global_load_lds((const glb_void*)gsrc, (lds_void*)ldst, 16, 0, 0); \
      } }

    f32x4 acc[2][5];
    const f32x4 vzero = {0.f, 0.f, 0.f, 0.f};
#pragma unroll
    for (int a = 0; a < 2; ++a)
#pragma unroll
        for (int b = 0; b < 5; ++b) acc[a][b] = vzero;

#define COMPUTE(b_)                                                            \
    { const char* bb_ = smem + (b_)*BUFB;                                      \
      bf16x8 Ar[2], Br[5];                                                     \
      _Pragma("unroll")                                                        \
      for (int rf = 0; rf < 2; ++rf)                                           \
          Ar[rf] = *(const bf16x8*)(bb_ + (rh * 2 + rf) * 1024 + l * 16);      \
      _Pragma("unroll")                                                        \
      for (int cf = 0; cf < 5; ++cf)                                           \
          Br[cf] = *(const bf16x8*)(bb_ + 4096 + (hc * 5 + cf) * 1024 + l * 16); \
      __builtin_amdgcn_s_setprio(1);                                           \
      _Pragma("unroll")                                                        \
      for (int cf = 0; cf < 5; ++cf) {                                         \
          acc[0][cf] = __builtin_amdgcn_mfma_f32_16x16x32_bf16(Ar[0], Br[cf], acc[0][cf], 0, 0, 0); \
          acc[1][cf] = __builtin_amdgcn_mfma_f32_16x16x32_bf16(Ar[1], Br[cf], acc[1][cf], 0, 0, 0); } \
      __builtin_amdgcn_s_setprio(0); }

    ISSUE(0, 0)
#pragma unroll 1
    for (int c = 0; c < 15; ++c) {
        ISSUE(c + 1, (c + 1) % 3)
        asm volatile("s_waitcnt vmcnt(3)" ::: "memory");   // chunk c landed; c+1 stays in flight
        __builtin_amdgcn_sched_barrier(0);
        __builtin_amdgcn_s_barrier();                      // raw: no vmcnt(0) drain
        COMPUTE(c % 3)
    }
    asm volatile("s_waitcnt vmcnt(0)" ::: "memory");
    __builtin_amdgcn_sched_barrier(0);
    __builtin_amdgcn_s_barrier();
    COMPUTE(0)                                             // chunk 15 -> buf 0

    // ---- epilogue: bias + gumbel, no-max softmax (exp into acc), packed-key argmax ----
    float bb[5];
#pragma unroll
    for (int cf = 0; cf < 5; ++cf) bb[cf] = bias[g * KK + hc * 80 + 16 * cf + ln];

    float gum[8][5];
#pragma unroll
    for (int rf = 0; rf < 2; ++rf)
#pragma unroll
        for (int reg = 0; reg < 4; ++reg) {
            const int row = 32 * rh + 16 * rf + 4 * q + reg;
            const float* gp = gumbel + ((size_t)(n0 + row) * GG + g) * KK + hc * 80 + ln;
#pragma unroll
            for (int cf = 0; cf < 5; ++cf) gum[rf * 4 + reg][cf] = gp[16 * cf];
        }
    __builtin_amdgcn_sched_barrier(0);

#pragma unroll
    for (int cf = 0; cf < 5; ++cf)
#pragma unroll
        for (int rf = 0; rf < 2; ++rf) {
            acc[rf][cf][0] += bb[cf]; acc[rf][cf][1] += bb[cf];
            acc[rf][cf][2] += bb[cf]; acc[rf][cf][3] += bb[cf];
        }

#pragma unroll
    for (int rf = 0; rf < 2; ++rf) {
#pragma unroll
        for (int reg = 0; reg < 4; ++reg) {
            const int row = 32 * rh + 16 * rf + 4 * q + reg;
            float s = 0.f, zm = -3.0e38f;
            int zi = 0;
#pragma unroll
            for (int cf = 0; cf < 5; ++cf) {
                float v = acc[rf][cf][reg];
                float z = v + gum[rf * 4 + reg][cf];
                if (z > zm) { zm = z; zi = hc * 80 + 16 * cf + ln; }  // in-lane: exact, first-index
                float e = __expf(v);
                s += e;
                acc[rf][cf][reg] = e;              // reuse in marginal
            }
            unsigned key = (ordf(zm) & 0xFFFFFE00u) | (unsigned)(511 - zi);
#pragma unroll
            for (int d = 1; d <= 8; d <<= 1) {
                s += __shfl_xor(s, d);
                unsigned ko = (unsigned)__shfl_xor((int)key, d);
                key = key > ko ? key : ko;
            }
            if (ln == 0) {
                const int base = row * 4 + hc;
                red_s[base] = s;
                red_k[base] = key;
            }
        }
    }
    __syncthreads();

    if (tid < 64) {
        const int b0 = tid * 4;
        float Z = red_s[b0] + red_s[b0 + 1] + red_s[b0 + 2] + red_s[b0 + 3];
        unsigned km = red_k[b0];
        km = km > red_k[b0 + 1] ? km : red_k[b0 + 1];
        km = km > red_k[b0 + 2] ? km : red_k[b0 + 2];
        km = km > red_k[b0 + 3] ? km : red_k[b0 + 3];
        const int ib = 511 - (int)(km & 511u);
        idxf[tid]  = ib;
        if (!fused) idxW[(size_t)(n0 + tid) * GG + g] = ib;
        wrowS[tid] = ((mask[n0 + tid] != 0) ? 1.0f : 0.0f) / Z;
    }
    __syncthreads();

    // ---- marginal (acc holds exp) ----
    float cs[5] = {0.f, 0.f, 0.f, 0.f, 0.f};
#pragma unroll
    for (int rf = 0; rf < 2; ++rf) {
#pragma unroll
        for (int reg = 0; reg < 4; ++reg) {
            const int row = 32 * rh + 16 * rf + 4 * q + reg;
            const float wv = wrowS[row];
#pragma unroll
            for (int cf = 0; cf < 5; ++cf)
                cs[cf] += acc[rf][cf][reg] * wv;
        }
    }
    {
        float* mc = marg + (size_t)(s_id & (NCPY - 1)) * (GG * KK);
#pragma unroll
        for (int cf = 0; cf < 5; ++cf) {
            float v = cs[cf];
            v += __shfl_xor(v, 16);
            v += __shfl_xor(v, 32);
            if (l < 16) atomicAdd(&mc[g * KK + hc * 80 + 16 * cf + l], v);
        }
    }

    // ---- fused codevector gather (Path A: out does NOT alias Hbf) ----
    if (fused) {
#pragma unroll
        for (int i = 0; i < 4; ++i) {
            const int e = tid + 512 * i;           // 2048 float4: 64 rows x 32
            const int row = e >> 5, d4 = e & 31;
            const float4 v = ((const float4*)cv)[((size_t)g * KK + idxf[row]) * 32 + d4];
            ((float4*)(out + (size_t)(n0 + row) * 256 + g * DPG))[d4] = v;
        }
    }

    // ---- last-block perplexity finalize (no __threadfence — r19 lesson) ----
    asm volatile("s_waitcnt vmcnt(0)" ::: "memory");   // marg atomics performed
    __syncthreads();
    if (tid == 0) {
        int old = atomicAdd(done, 1);
        lastflag = (old == 2047) ? 1 : 0;
    }
    __syncthreads();
    if (lastflag) {
        const float invc = 1.0f / cnt_in[0];
        float hg[GG];
#pragma unroll
        for (int gg = 0; gg < GG; ++gg) {
            float h = 0.f;
            for (int c = tid; c < KK; c += 512) {
                float m = 0.f;
#pragma unroll
                for (int x = 0; x < NCPY; ++x)
                    m += atomicAdd(&marg[x * (GG * KK) + gg * KK + c], 0.0f);
                m *= invc;
                h += m * logf(m + EPSL);
            }
#pragma unroll
            for (int d = 1; d < 64; d <<= 1) h += __shfl_xor(h, d);
            if (l == 0) red_s[wid] = h;
            __syncthreads();
            if (tid == 0) {
                float t = 0.f;
                for (int wv = 0; wv < 8; ++wv) t += red_s[wv];
                red_s[64 + gg] = t;
            }
            __syncthreads();
            hg[gg] = red_s[64 + gg];
        }
        if (tid == 0) perp_out[0] = expf(-hg[0]) + expf(-hg[1]);   // base-e
    }
}

// ---------- Path B gather (pure) ----------
__global__ __launch_bounds__(256) void gather_kernel(
    const int* __restrict__ idxW, const float* __restrict__ cv,
    float* __restrict__ out)
{
    const int e = blockIdx.x * 256 + threadIdx.x;     // 4,194,304 float4 slots
    const int n = e >> 6, s4 = e & 63, g = s4 >> 5, d4 = s4 & 31;
    const int idx = idxW[(size_t)n * GG + g];
    const float4 v = ((const float4*)cv)[((size_t)g * KK + idx) * 32 + d4];
    ((float4*)out)[e] = v;
}

extern "C" void kernel_launch(void* const* d_in, const int* in_sizes, int n_in,
                              void* d_out, int out_size, void* d_ws, size_t ws_size,
                              hipStream_t stream)
{
    const float* H      = (const float*)d_in[0];   // (32,2048,512) f32
    const int*   mask   = (const int*)d_in[1];     // (32,2048) bool->int32
    const float* gumbel = (const float*)d_in[2];   // (131072,320) f32
    const float* W      = (const float*)d_in[3];   // (640,512) f32
    const float* bias   = (const float*)d_in[4];   // (640,) f32
    const float* cv     = (const float*)d_in[5];   // (1,640,128) f32

    float*  out  = (float*)d_out;                  // 16,777,216 + 1 floats
    float*  marg = (float*)d_ws;                   // 8 copies x 640 f32 (20.5 KB)
    float*  cnt  = (float*)((char*)d_ws + 24576);  // mask count
    int*    done = (int*)((char*)d_ws + 24580);    // completion counter
    short*  Wf   = (short*)((char*)d_ws + 32768);  // 0.655 MB bf16 frags
    int*    idxW = (int*)((char*)d_ws + 32768 + 655360);  // 131072 ints

    const size_t hbf_off  = 2 * 1024 * 1024;
    const size_t hbf_need = hbf_off + (size_t)64 * 1024 * 1024;
    const int fused = (ws_size >= hbf_need) ? 1 : 0;
    short* Hbf = fused ? (short*)((char*)d_ws + hbf_off) : (short*)d_out;

    prep_all<<<16545, 256, 0, stream>>>(H, Hbf, W, Wf, marg, mask, cnt, done);
    vq_main<<<2048, 512, 0, stream>>>(Hbf, mask, gumbel, Wf, bias, cv, idxW, marg,
                                      fused, out, cnt, done,
                                      out + (size_t)NN * GG * DPG);
    if (!fused)
        gather_kernel<<<16384, 256, 0, stream>>>(idxW, cv, out);
}

// Round 24
// 131.446 us; speedup vs baseline: 1.0394x; 1.0319x over previous
//
#include <hip/hip_runtime.h>

// Wav2Vec2 Gumbel VQ — round 24: byte-for-byte restore of r21 (measured best,
// 132.3us total). r22 (2-buffer: no 3rd block materialized, -7%) and r23
// (XCD swizzle: L3-fit working set, -2%) both reverted per A/B results.
// Structure: prep_all (downcast+Wfrag+misc, ~15us, HBM-floor) -> vq_main
// (DMA-transposed A, 3-buf pipelined global_load_lds GEMM, fused epilogue +
// gather + last-block finalize, ~108us) [+ Path-B gather if small ws].

#define GG   2
#define KK   320
#define NN   65536
#define DD   512
#define DPG  128
#define EPSL 1e-7f
#define NCPY 8
#define BUFB 24576   // bytes per LDS chunk buffer: 4 A frags + 20 B frags

typedef __attribute__((ext_vector_type(8))) short bf16x8;   // 8 x bf16
typedef __attribute__((ext_vector_type(4))) float f32x4;
typedef __attribute__((address_space(1))) void glb_void;
typedef __attribute__((address_space(3))) void lds_void;

static __device__ __forceinline__ unsigned short f2bf_rne(float f) {
    unsigned u = __float_as_uint(f);
    u += 0x7FFFu + ((u >> 16) & 1u);
    return (unsigned short)(u >> 16);
}

static __device__ __forceinline__ bf16x8 pack8_rne(float4 v0, float4 v1) {
    union { unsigned short s[8]; bf16x8 b; } u;
    u.s[0] = f2bf_rne(v0.x); u.s[1] = f2bf_rne(v0.y);
    u.s[2] = f2bf_rne(v0.z); u.s[3] = f2bf_rne(v0.w);
    u.s[4] = f2bf_rne(v1.x); u.s[5] = f2bf_rne(v1.y);
    u.s[6] = f2bf_rne(v1.z); u.s[7] = f2bf_rne(v1.w);
    return u.b;
}

// monotone uint map: f1 < f2  <=>  ordf(f1) < ordf(f2)
static __device__ __forceinline__ unsigned ordf(float f) {
    unsigned u = __float_as_uint(f);
    return (u & 0x80000000u) ? ~u : (u | 0x80000000u);
}

// ---------- fused prep: H->bf16 row-major (sequential), W->Wf frags, misc ----------
__global__ __launch_bounds__(256) void prep_all(
    const float* __restrict__ H, short* __restrict__ Hbf,
    const float* __restrict__ W, short* __restrict__ Wf,
    float* __restrict__ marg, const int* __restrict__ mask,
    float* __restrict__ cnt_out, int* __restrict__ done)
{
    const int b = blockIdx.x, tid = threadIdx.x;
    if (b < 16384) {
        const size_t base = ((size_t)b * 256 + tid) * 8;
        float4 v0 = *(const float4*)(H + base);
        float4 v1 = *(const float4*)(H + base + 4);
        *(bf16x8*)(Hbf + base) = pack8_rne(v0, v1);
    } else if (b < 16544) {
        int gt = (b - 16384) * 256 + tid;
        int w  = gt >> 6, l = gt & 63;
        int col = 16 * (w >> 4) + (l & 15);
        int k0  = 32 * (w & 15) + 8 * (l >> 4);
        const float* src = W + (size_t)col * DD + k0;
        float4 v0 = *(const float4*)(src);
        float4 v1 = *(const float4*)(src + 4);
        *(bf16x8*)(Wf + (size_t)w * 512 + (size_t)l * 8) = pack8_rne(v0, v1);
    } else {
        __shared__ float red[256];
        for (int i = tid; i < NCPY * GG * KK; i += 256) marg[i] = 0.f;
        if (tid == 0) *done = 0;
        const int4* m4 = (const int4*)mask;
        int c = 0;
#pragma unroll 4
        for (int i = tid; i < NN / 4; i += 256) {
            int4 v = m4[i];
            c += (v.x != 0) + (v.y != 0) + (v.z != 0) + (v.w != 0);
        }
        red[tid] = (float)c;
        __syncthreads();
        for (int s = 128; s > 0; s >>= 1) {
            if (tid < s) red[tid] += red[tid + s];
            __syncthreads();
        }
        if (tid == 0) *cnt_out = red[0];
    }
}

// ---------- main: GEMM + softmax/argmax/marginal + gather + last-block finalize ----------
// grid 2048 = 1024 row-tiles (64 rows) x 2 groups; 512 thr = 8 waves.
// K-loop (r16/r21 proven): ISSUE(c+1) -> vmcnt(3) -> raw s_barrier -> COMPUTE(c).
// A frags DMA'd from ROW-MAJOR Hbf via per-lane source addresses (m173).
__global__ __launch_bounds__(512, 4) void vq_main(
    const short* Hbf, const int* __restrict__ mask,
    const float* __restrict__ gumbel, const short* __restrict__ Wf,
    const float* __restrict__ bias, const float* __restrict__ cv,
    int* __restrict__ idxW, float* marg,
    int fused, float* __restrict__ out,
    const float* __restrict__ cnt_in, int* done, float* __restrict__ perp_out)
{
    __shared__ __align__(16) char smem[3 * BUFB];     // 72 KB: 3 chunk buffers
    __shared__ float    red_s[256];
    __shared__ unsigned red_k[256];
    __shared__ float    wrowS[64];
    __shared__ int      idxf[64];
    __shared__ int      lastflag;

    const int tid = threadIdx.x;
    const int l   = tid & 63, wid = tid >> 6;
    const int rh  = wid >> 2, hc = wid & 3;
    const int g   = blockIdx.x & 1;
    const int T   = blockIdx.x >> 1;
    const int n0  = T * 64;
    const int q   = l >> 4,  ln = l & 15;

    // hoisted per-lane DMA source bases (t=0) + per-chunk byte strides.
    // k<4: A frag from row-major Hbf (lane l -> row n0+16k+(l&15), col 8*(l>>4)); step 64B.
    // k>=4: B frag from fragment-ordered Wf; step 1024B.
    const short* gsrc0[3];
    int stepB[3];
#pragma unroll
    for (int j = 0; j < 3; ++j) {
        const int k = wid * 3 + j;
        if (k < 4) {
            gsrc0[j] = Hbf + (size_t)(n0 + 16 * k + (l & 15)) * 512 + 8 * (l >> 4);
            stepB[j] = 64;
        } else {
            gsrc0[j] = Wf + (size_t)((g * 20 + (k - 4)) * 16) * 512 + (size_t)l * 8;
            stepB[j] = 1024;
        }
    }

#define ISSUE(t_, b_)                                                          \
    { _Pragma("unroll")                                                        \
      for (int j = 0; j < 3; ++j) {                                            \
          const int k = wid * 3 + j;                                           \
          const short* gsrc = (const short*)((const char*)gsrc0[j] + (t_) * stepB[j]); \
          char* ldst = smem + (b_)*BUFB + k * 1024;                            \
          __builtin_amdgcn_global_load_lds((const glb_void*)gsrc, (lds_void*)ldst, 16, 0, 0); \
      } }

    f32x4 acc[2][5];
    const f32x4 vzero = {0.f, 0.f, 0.f, 0.f};
#pragma unroll
    for (int a = 0; a < 2; ++a)
#pragma unroll
        for (int b = 0; b < 5; ++b) acc[a][b] = vzero;

#define COMPUTE(b_)                                                            \
    { const char* bb_ = smem + (b_)*BUFB;                                      \
      bf16x8 Ar[2], Br[5];                                                     \
      _Pragma("unroll")                                                        \
      for (int rf = 0; rf < 2; ++rf)                                           \
          Ar[rf] = *(const bf16x8*)(bb_ + (rh * 2 + rf) * 1024 + l * 16);      \
      _Pragma("unroll")                                                        \
      for (int cf = 0; cf < 5; ++cf)                                           \
          Br[cf] = *(const bf16x8*)(bb_ + 4096 + (hc * 5 + cf) * 1024 + l * 16); \
      __builtin_amdgcn_s_setprio(1);                                           \
      _Pragma("unroll")                                                        \
      for (int cf = 0; cf < 5; ++cf) {                                         \
          acc[0][cf] = __builtin_amdgcn_mfma_f32_16x16x32_bf16(Ar[0], Br[cf], acc[0][cf], 0, 0, 0); \
          acc[1][cf] = __builtin_amdgcn_mfma_f32_16x16x32_bf16(Ar[1], Br[cf], acc[1][cf], 0, 0, 0); } \
      __builtin_amdgcn_s_setprio(0); }

    ISSUE(0, 0)
#pragma unroll 1
    for (int c = 0; c < 15; ++c) {
        ISSUE(c + 1, (c + 1) % 3)
        asm volatile("s_waitcnt vmcnt(3)" ::: "memory");   // chunk c landed; c+1 stays in flight
        __builtin_amdgcn_sched_barrier(0);
        __builtin_amdgcn_s_barrier();                      // raw: no vmcnt(0) drain
        COMPUTE(c % 3)
    }
    asm volatile("s_waitcnt vmcnt(0)" ::: "memory");
    __builtin_amdgcn_sched_barrier(0);
    __builtin_amdgcn_s_barrier();
    COMPUTE(0)                                             // chunk 15 -> buf 0

    // ---- epilogue: bias + gumbel, no-max softmax (exp into acc), packed-key argmax ----
    float bb[5];
#pragma unroll
    for (int cf = 0; cf < 5; ++cf) bb[cf] = bias[g * KK + hc * 80 + 16 * cf + ln];

    float gum[8][5];
#pragma unroll
    for (int rf = 0; rf < 2; ++rf)
#pragma unroll
        for (int reg = 0; reg < 4; ++reg) {
            const int row = 32 * rh + 16 * rf + 4 * q + reg;
            const float* gp = gumbel + ((size_t)(n0 + row) * GG + g) * KK + hc * 80 + ln;
#pragma unroll
            for (int cf = 0; cf < 5; ++cf) gum[rf * 4 + reg][cf] = gp[16 * cf];
        }
    __builtin_amdgcn_sched_barrier(0);

#pragma unroll
    for (int cf = 0; cf < 5; ++cf)
#pragma unroll
        for (int rf = 0; rf < 2; ++rf) {
            acc[rf][cf][0] += bb[cf]; acc[rf][cf][1] += bb[cf];
            acc[rf][cf][2] += bb[cf]; acc[rf][cf][3] += bb[cf];
        }

#pragma unroll
    for (int rf = 0; rf < 2; ++rf) {
#pragma unroll
        for (int reg = 0; reg < 4; ++reg) {
            const int row = 32 * rh + 16 * rf + 4 * q + reg;
            float s = 0.f, zm = -3.0e38f;
            int zi = 0;
#pragma unroll
            for (int cf = 0; cf < 5; ++cf) {
                float v = acc[rf][cf][reg];
                float z = v + gum[rf * 4 + reg][cf];
                if (z > zm) { zm = z; zi = hc * 80 + 16 * cf + ln; }  // in-lane: exact, first-index
                float e = __expf(v);
                s += e;
                acc[rf][cf][reg] = e;              // reuse in marginal
            }
            unsigned key = (ordf(zm) & 0xFFFFFE00u) | (unsigned)(511 - zi);
#pragma unroll
            for (int d = 1; d <= 8; d <<= 1) {
                s += __shfl_xor(s, d);
                unsigned ko = (unsigned)__shfl_xor((int)key, d);
                key = key > ko ? key : ko;
            }
            if (ln == 0) {
                const int base = row * 4 + hc;
                red_s[base] = s;
                red_k[base] = key;
            }
        }
    }
    __syncthreads();

    if (tid < 64) {
        const int b0 = tid * 4;
        float Z = red_s[b0] + red_s[b0 + 1] + red_s[b0 + 2] + red_s[b0 + 3];
        unsigned km = red_k[b0];
        km = km > red_k[b0 + 1] ? km : red_k[b0 + 1];
        km = km > red_k[b0 + 2] ? km : red_k[b0 + 2];
        km = km > red_k[b0 + 3] ? km : red_k[b0 + 3];
        const int ib = 511 - (int)(km & 511u);
        idxf[tid]  = ib;
        if (!fused) idxW[(size_t)(n0 + tid) * GG + g] = ib;
        wrowS[tid] = ((mask[n0 + tid] != 0) ? 1.0f : 0.0f) / Z;
    }
    __syncthreads();

    // ---- marginal (acc holds exp) ----
    float cs[5] = {0.f, 0.f, 0.f, 0.f, 0.f};
#pragma unroll
    for (int rf = 0; rf < 2; ++rf) {
#pragma unroll
        for (int reg = 0; reg < 4; ++reg) {
            const int row = 32 * rh + 16 * rf + 4 * q + reg;
            const float wv = wrowS[row];
#pragma unroll
            for (int cf = 0; cf < 5; ++cf)
                cs[cf] += acc[rf][cf][reg] * wv;
        }
    }
    {
        float* mc = marg + (size_t)(blockIdx.x & (NCPY - 1)) * (GG * KK);
#pragma unroll
        for (int cf = 0; cf < 5; ++cf) {
            float v = cs[cf];
            v += __shfl_xor(v, 16);
            v += __shfl_xor(v, 32);
            if (l < 16) atomicAdd(&mc[g * KK + hc * 80 + 16 * cf + l], v);
        }
    }

    // ---- fused codevector gather (Path A: out does NOT alias Hbf) ----
    if (fused) {
#pragma unroll
        for (int i = 0; i < 4; ++i) {
            const int e = tid + 512 * i;           // 2048 float4: 64 rows x 32
            const int row = e >> 5, d4 = e & 31;
            const float4 v = ((const float4*)cv)[((size_t)g * KK + idxf[row]) * 32 + d4];
            ((float4*)(out + (size_t)(n0 + row) * 256 + g * DPG))[d4] = v;
        }
    }

    // ---- last-block perplexity finalize (no __threadfence — r19 lesson) ----
    asm volatile("s_waitcnt vmcnt(0)" ::: "memory");   // marg atomics performed
    __syncthreads();
    if (tid == 0) {
        int old = atomicAdd(done, 1);
        lastflag = (old == 2047) ? 1 : 0;
    }
    __syncthreads();
    if (lastflag) {
        const float invc = 1.0f / cnt_in[0];
        float hg[GG];
#pragma unroll
        for (int gg = 0; gg < GG; ++gg) {
            float h = 0.f;
            for (int c = tid; c < KK; c += 512) {
                float m = 0.f;
#pragma unroll
                for (int x = 0; x < NCPY; ++x)
                    m += atomicAdd(&marg[x * (GG * KK) + gg * KK + c], 0.0f);
                m *= invc;
                h += m * logf(m + EPSL);
            }
#pragma unroll
            for (int d = 1; d < 64; d <<= 1) h += __shfl_xor(h, d);
            if (l == 0) red_s[wid] = h;
            __syncthreads();
            if (tid == 0) {
                float t = 0.f;
                for (int wv = 0; wv < 8; ++wv) t += red_s[wv];
                red_s[64 + gg] = t;
            }
            __syncthreads();
            hg[gg] = red_s[64 + gg];
        }
        if (tid == 0) perp_out[0] = expf(-hg[0]) + expf(-hg[1]);   // base-e
    }
}

// ---------- Path B gather (pure) ----------
__global__ __launch_bounds__(256) void gather_kernel(
    const int* __restrict__ idxW, const float* __restrict__ cv,
    float* __restrict__ out)
{
    const int e = blockIdx.x * 256 + threadIdx.x;     // 4,194,304 float4 slots
    const int n = e >> 6, s4 = e & 63, g = s4 >> 5, d4 = s4 & 31;
    const int idx = idxW[(size_t)n * GG + g];
    const float4 v = ((const float4*)cv)[((size_t)g * KK + idx) * 32 + d4];
    ((float4*)out)[e] = v;
}

extern "C" void kernel_launch(void* const* d_in, const int* in_sizes, int n_in,
                              void* d_out, int out_size, void* d_ws, size_t ws_size,
                              hipStream_t stream)
{
    const float* H      = (const float*)d_in[0];   // (32,2048,512) f32
    const int*   mask   = (const int*)d_in[1];     // (32,2048) bool->int32
    const float* gumbel = (const float*)d_in[2];   // (131072,320) f32
    const float* W      = (const float*)d_in[3];   // (640,512) f32
    const float* bias   = (const float*)d_in[4];   // (640,) f32
    const float* cv     = (const float*)d_in[5];   // (1,640,128) f32

    float*  out  = (float*)d_out;                  // 16,777,216 + 1 floats
    float*  marg = (float*)d_ws;                   // 8 copies x 640 f32 (20.5 KB)
    float*  cnt  = (float*)((char*)d_ws + 24576);  // mask count
    int*    done = (int*)((char*)d_ws + 24580);    // completion counter
    short*  Wf   = (short*)((char*)d_ws + 32768);  // 0.655 MB bf16 frags
    int*    idxW = (int*)((char*)d_ws + 32768 + 655360);  // 131072 ints

    const size_t hbf_off  = 2 * 1024 * 1024;
    const size_t hbf_need = hbf_off + (size_t)64 * 1024 * 1024;
    const int fused = (ws_size >= hbf_need) ? 1 : 0;
    short* Hbf = fused ? (short*)((char*)d_ws + hbf_off) : (short*)d_out;

    prep_all<<<16545, 256, 0, stream>>>(H, Hbf, W, Wf, marg, mask, cnt, done);
    vq_main<<<2048, 512, 0, stream>>>(Hbf, mask, gumbel, Wf, bias, cv, idxW, marg,
                                      fused, out, cnt, done,
                                      out + (size_t)NN * GG * DPG);
    if (!fused)
        gather_kernel<<<16384, 256, 0, stream>>>(idxW, cv, out);
}